// Round 7
// baseline (5129.575 us; speedup 1.0000x reference)
//
#include <hip/hip_runtime.h>
#include <cstdint>

// MambaBlock: out = (silu(x@in_w[:1024]^T+b0) * silu(x@in_w[1024:]^T+b1)) @ out_w^T + out_b
// M = 32768, K = 1024. dt_w/dt_b/A/Dp are dead inputs.
//
// Round 7: 256x512 block tile, per-wave 128x128 (8 waves 2Mx4N over N=512):
// LDS-read volume per FLOP drops 1.5x (A-redundancy 4->2), MFMA becomes the
// binding resource. 3 LDS buffers x 48 KiB = 144 KiB, 1 block/CU (already the
// case before). BK=32, counted WAITB(6) (depth-2 prefetch, never vmcnt 0 in
// main loop), 32x32x16 MFMA, swizzle key2(row)=((row>>1)^(row>>4))&3 on both
// stage-source and ds_read (r6: measured 0 conflicts), setprio, XCD swizzle,
// shuffle-free paired-silu epilogue (blk32-interleaved W1).

typedef __bf16 bf16x8 __attribute__((ext_vector_type(8)));
typedef float f32x16 __attribute__((ext_vector_type(16)));

#define KD 1024
#define BUF_ELEMS 24576  // per buffer: A 256x32 (8192) + B 512x32 (16384) elems

__device__ __forceinline__ void gload_lds16(const void* g, void* lds_u) {
  __builtin_amdgcn_global_load_lds(
      (__attribute__((address_space(1))) void*)(uintptr_t)g,
      (__attribute__((address_space(3))) void*)(uint32_t)(uintptr_t)lds_u,
      16, 0, 0);
}

#define WAITB(N) do { \
  asm volatile("s_waitcnt vmcnt(" #N ")" ::: "memory"); \
  asm volatile("s_barrier" ::: "memory"); } while (0)

// ---------------- casts ----------------
__global__ void cast_f32_to_bf16_x8(const float* __restrict__ in,
                                    __bf16* __restrict__ out, int n8) {
  int i = blockIdx.x * blockDim.x + threadIdx.x;
  if (i >= n8) return;
  const float4* p = (const float4*)in;
  float4 v0 = p[2 * i];
  float4 v1 = p[2 * i + 1];
  bf16x8 o;
  o[0] = (__bf16)v0.x; o[1] = (__bf16)v0.y; o[2] = (__bf16)v0.z; o[3] = (__bf16)v0.w;
  o[4] = (__bf16)v1.x; o[5] = (__bf16)v1.y; o[6] = (__bf16)v1.z; o[7] = (__bf16)v1.w;
  ((bf16x8*)out)[i] = o;
}

// W1'' 32-row block interleave: out-row r, b=r>>5, t=r&31:
//   src row = (b&1)*1024 + (b>>1)*32 + t
// => adjacent 32-row blocks pair x_val/res for the SAME G columns.
__global__ void cast_w1_blk32(const float* __restrict__ in,
                              __bf16* __restrict__ out) {
  int i = blockIdx.x * blockDim.x + threadIdx.x;  // 2048*128 threads
  int orow = i >> 7;
  int chunk = i & 127;
  int b = orow >> 5, t = orow & 31;
  int srow = (b & 1) * 1024 + (b >> 1) * 32 + t;
  const float4* p = (const float4*)(in + ((size_t)srow << 10) + (chunk << 3));
  float4 v0 = p[0], v1 = p[1];
  bf16x8 o;
  o[0] = (__bf16)v0.x; o[1] = (__bf16)v0.y; o[2] = (__bf16)v0.z; o[3] = (__bf16)v0.w;
  o[4] = (__bf16)v1.x; o[5] = (__bf16)v1.y; o[6] = (__bf16)v1.z; o[7] = (__bf16)v1.w;
  *(bf16x8*)(out + ((size_t)orow << 10) + (chunk << 3)) = o;
}

// ---------------- GEMM core ----------------
// Stage one K-tile (A 256x32 + B 512x32 = 48 KiB) into buffer BUF.
// 6 gloads per wave: 2 for A (16 rows each), 4 for B.
template <int BUF>
__device__ __forceinline__ void stage_tile(const __bf16*& pa, const __bf16*& pb,
                                           int ca0, int ca1,
                                           int cb0, int cb1, int cb2, int cb3,
                                           __bf16* dA, __bf16* dB) {
  __bf16* a = dA + BUF * BUF_ELEMS;
  __bf16* b = dB + BUF * BUF_ELEMS;
  gload_lds16(pa + ca0, a);
  gload_lds16(pa + 16 * KD + ca1, a + 512);
  gload_lds16(pb + cb0, b);
  gload_lds16(pb + 16 * KD + cb1, b + 512);
  gload_lds16(pb + 32 * KD + cb2, b + 1024);
  gload_lds16(pb + 48 * KD + cb3, b + 1536);
  pa += 32;
  pb += 32;
}

// 32x32x16 MFMA; per K-tile: 16 ds_read_b128 (8 A + 8 B), 32 MFMA.
// Chunk swizzle phys = logical ^ key2(row); frag idx parity (i&1 / j&1)
// flips the chunk offset between o0 and o1 = o0^16.
template <int BUF>
__device__ __forceinline__ void compute_tile(const __bf16* sm,
                                             int aRow, int bRow,
                                             int o0, int o1,
                                             f32x16 (&acc)[4][4]) {
  const __bf16* base = sm + BUF * BUF_ELEMS;
  bf16x8 a0[4], a1[4], b0[4], b1[4];
#pragma unroll
  for (int j = 0; j < 4; ++j) {
    const int e0 = (j & 1) ? o1 : o0;
    const int e1 = (j & 1) ? o0 : o1;
    b0[j] = *(const bf16x8*)(base + bRow + j * 1024 + e0);
    b1[j] = *(const bf16x8*)(base + bRow + j * 1024 + e1);
  }
#pragma unroll
  for (int i = 0; i < 4; ++i) {
    const int e0 = (i & 1) ? o1 : o0;
    const int e1 = (i & 1) ? o0 : o1;
    a0[i] = *(const bf16x8*)(base + aRow + i * 1024 + e0);
    a1[i] = *(const bf16x8*)(base + aRow + i * 1024 + e1);
  }
  __builtin_amdgcn_s_setprio(1);
#pragma unroll
  for (int i = 0; i < 4; ++i)
#pragma unroll
    for (int j = 0; j < 4; ++j)
      acc[i][j] = __builtin_amdgcn_mfma_f32_32x32x16_bf16(a0[i], b0[j], acc[i][j], 0, 0, 0);
#pragma unroll
  for (int i = 0; i < 4; ++i)
#pragma unroll
    for (int j = 0; j < 4; ++j)
      acc[i][j] = __builtin_amdgcn_mfma_f32_32x32x16_bf16(a1[i], b1[j], acc[i][j], 0, 0, 0);
  __builtin_amdgcn_s_setprio(0);
}

// Fills acc for the 256x512 tile at (m0, n0). A:[M][1024], B:[Nrows][1024].
__device__ __forceinline__ void gemm_core(const __bf16* __restrict__ A,
                                          const __bf16* __restrict__ B,
                                          __bf16* sm, long m0, long n0,
                                          f32x16 (&acc)[4][4]) {
  const int t = threadIdx.x;
  const int w = t >> 6;
  const int lane = t & 63;
  const int c31 = lane & 31;
  const int hi = lane >> 5;
  const int wr = w >> 2;  // 0..1 (M)
  const int wc = w & 3;   // 0..3 (N, 128 each)

  // staging: A rows w*32 + inst*16 + (l>>2); B rows w*64 + binst*16 + (l>>2).
  // phys slot l&3 holds logical chunk (l&3)^key2(row);
  // key2_A = ((l>>3)&3)^((2w+inst)&3); key2_B = ((l>>3)&3)^(binst&3).
  const int l = lane;
  const int base_x = (l & 3) ^ ((l >> 3) & 3);
  const int ca0 = (base_x ^ ((2 * w) & 3)) << 3;
  const int ca1 = (base_x ^ ((2 * w + 1) & 3)) << 3;
  const int cb0 = base_x << 3;
  const int cb1 = (base_x ^ 1) << 3;
  const int cb2 = (base_x ^ 2) << 3;
  const int cb3 = (base_x ^ 3) << 3;
  const __bf16* pa = A + (m0 + w * 32 + (l >> 2)) * KD;
  const __bf16* pb = B + (n0 + w * 64 + (l >> 2)) * KD;
  __bf16* dA = sm + w * 1024;          // wave-uniform
  __bf16* dB = sm + 8192 + w * 2048;   // B region starts at elem 8192

  // fragment reads: row = (wr|wc)*128 + idx*32 + c31;
  // key2 = ((c31>>1)&3) ^ ((c31>>4)&3), idx parity flips chunk bit 1.
  const int key_base = ((c31 >> 1) & 3) ^ ((c31 >> 4) & 3);
  const int o0 = (hi ^ key_base) << 3;
  const int o1 = o0 ^ 16;
  const int aRow = (wr * 128 + c31) * 32;          // + i*1024
  const int bRow = 8192 + (wc * 128 + c31) * 32;   // + j*1024

#pragma unroll
  for (int i = 0; i < 4; ++i)
#pragma unroll
    for (int j = 0; j < 4; ++j)
      acc[i][j] = (f32x16){0.f, 0.f, 0.f, 0.f, 0.f, 0.f, 0.f, 0.f,
                           0.f, 0.f, 0.f, 0.f, 0.f, 0.f, 0.f, 0.f};

  // prologue: stage tiles 0,1 (12 loads in flight)
  stage_tile<0>(pa, pb, ca0, ca1, cb0, cb1, cb2, cb3, dA, dB);
  stage_tile<1>(pa, pb, ca0, ca1, cb0, cb1, cb2, cb3, dA, dB);

  // tiles 0..29: compute buf t%3, stage tile t+2 into buf (t+2)%3
  for (int it = 0; it < 10; ++it) {
    WAITB(6); stage_tile<2>(pa, pb, ca0, ca1, cb0, cb1, cb2, cb3, dA, dB);
    compute_tile<0>(sm, aRow, bRow, o0, o1, acc);
    WAITB(6); stage_tile<0>(pa, pb, ca0, ca1, cb0, cb1, cb2, cb3, dA, dB);
    compute_tile<1>(sm, aRow, bRow, o0, o1, acc);
    WAITB(6); stage_tile<1>(pa, pb, ca0, ca1, cb0, cb1, cb2, cb3, dA, dB);
    compute_tile<2>(sm, aRow, bRow, o0, o1, acc);
  }
  // tail: tiles 30 (buf0), 31 (buf1)
  WAITB(6); compute_tile<0>(sm, aRow, bRow, o0, o1, acc);
  WAITB(0); compute_tile<1>(sm, aRow, bRow, o0, o1, acc);
}

// ---------------- GEMM1: Y = X @ W1''^T, paired-silu epilogue -> G bf16 -----
// N_total = 2048 (blk32-interleaved); tile N=512 -> 4 n-tiles, 512 blocks.
__global__ __launch_bounds__(512, 1)
void gemm1_silu(const __bf16* __restrict__ X, const __bf16* __restrict__ W1i,
                const float* __restrict__ in_b, __bf16* __restrict__ G) {
  __shared__ __bf16 sm[3 * BUF_ELEMS];  // 144 KiB
  // XCD-aware bijective swizzle: nwg = 512, divisible by 8
  const int bid = blockIdx.x;
  const int swz = (bid & 7) * 64 + (bid >> 3);
  const long m0 = (long)(swz >> 2) * 256;
  const long n0 = (long)(swz & 3) * 512;

  f32x16 acc[4][4];
  gemm_core(X, W1i, sm, m0, n0, acc);

  const int lane = threadIdx.x & 63;
  const int w = threadIdx.x >> 6;
  const int wr = w >> 2, wc = w & 3;
  const int c31 = lane & 31;
  const int hi = lane >> 5;

  // pair p: j=2p (x_val block), j=2p+1 (res block); same G columns.
  float bx[2], br[2];
#pragma unroll
  for (int p = 0; p < 2; ++p) {
    const int gc = ((int)n0 >> 1) + wc * 64 + p * 32 + c31;
    bx[p] = in_b[gc];
    br[p] = in_b[1024 + gc];
  }
#pragma unroll
  for (int i = 0; i < 4; ++i)
#pragma unroll
    for (int p = 0; p < 2; ++p) {
      const int gc = ((int)n0 >> 1) + wc * 64 + p * 32 + c31;
#pragma unroll
      for (int reg = 0; reg < 16; ++reg) {
        const int row = wr * 128 + i * 32 + (reg & 3) + 8 * (reg >> 2) + 4 * hi;
        float xv = acc[i][2 * p][reg] + bx[p];
        float rs = acc[i][2 * p + 1][reg] + br[p];
        float e1 = __expf(-xv);
        float e2 = __expf(-rs);
        float g = xv * rs * __builtin_amdgcn_rcpf((1.0f + e1) * (1.0f + e2));
        G[(m0 + row) * 1024 + gc] = (__bf16)g;
      }
    }
}

// ---------------- GEMM2: OUT = G @ W2^T + out_b (fp32) ----------------
// N = 1024 -> 2 n-tiles, 256 blocks.
__global__ __launch_bounds__(512, 1)
void gemm2_bias(const __bf16* __restrict__ G, const __bf16* __restrict__ W2,
                const float* __restrict__ out_b, float* __restrict__ OUT) {
  __shared__ __bf16 sm[3 * BUF_ELEMS];
  // nwg = 256, divisible by 8
  const int bid = blockIdx.x;
  const int swz = (bid & 7) * 32 + (bid >> 3);
  const long m0 = (long)(swz >> 1) * 256;
  const long n0 = (long)(swz & 1) * 512;

  f32x16 acc[4][4];
  gemm_core(G, W2, sm, m0, n0, acc);

  const int lane = threadIdx.x & 63;
  const int w = threadIdx.x >> 6;
  const int wr = w >> 2, wc = w & 3;
  const int c31 = lane & 31;
  const int hi = lane >> 5;

  float ob[4];
#pragma unroll
  for (int j = 0; j < 4; ++j)
    ob[j] = out_b[(int)n0 + wc * 128 + j * 32 + c31];
#pragma unroll
  for (int i = 0; i < 4; ++i)
#pragma unroll
    for (int j = 0; j < 4; ++j) {
      const int col = (int)n0 + wc * 128 + j * 32 + c31;
#pragma unroll
      for (int reg = 0; reg < 16; ++reg) {
        const int row = wr * 128 + i * 32 + (reg & 3) + 8 * (reg >> 2) + 4 * hi;
        OUT[(m0 + row) * 1024 + col] = acc[i][j][reg] + ob[j];
      }
    }
}

extern "C" void kernel_launch(void* const* d_in, const int* in_sizes, int n_in,
                              void* d_out, int out_size, void* d_ws, size_t ws_size,
                              hipStream_t stream) {
  const float* x = (const float*)d_in[0];
  const float* in_w = (const float*)d_in[1];
  const float* in_b = (const float*)d_in[2];
  const float* out_w = (const float*)d_in[3];
  const float* out_b = (const float*)d_in[4];
  // d_in[5..8] (dt_w, dt_b, A, Dp) are dead in the reference.

  char* ws = (char*)d_ws;
  __bf16* xb = (__bf16*)(ws);                       // 67108864 B
  __bf16* w1b = (__bf16*)(ws + (size_t)67108864);   //  4194304 B (blk32 interleaved)
  __bf16* w2b = (__bf16*)(ws + (size_t)71303168);   //  2097152 B
  __bf16* gb = (__bf16*)(ws + (size_t)73400320);    // 67108864 B

  cast_f32_to_bf16_x8<<<dim3(16384), 256, 0, stream>>>(x, xb, 33554432 / 8);
  cast_w1_blk32<<<dim3(1024), 256, 0, stream>>>(in_w, w1b);
  cast_f32_to_bf16_x8<<<dim3(512), 256, 0, stream>>>(out_w, w2b, 1048576 / 8);

  gemm1_silu<<<dim3(512), 512, 0, stream>>>(xb, w1b, in_b, gb);
  gemm2_bias<<<dim3(256), 512, 0, stream>>>(gb, w2b, out_b, (float*)d_out);
}

// Round 8
// 3786.456 us; speedup vs baseline: 1.3547x; 1.3547x over previous
//
#include <hip/hip_runtime.h>
#include <cstdint>

// MambaBlock: out = (silu(x@in_w[:1024]^T+b0) * silu(x@in_w[1024:]^T+b1)) @ out_w^T + out_b
// M = 32768, K = 1024. dt_w/dt_b/A/Dp are dead inputs.
//
// Core: 256x256 tile, BK=32, 512 threads (8 waves, 2Mx4N), 32x32x16 MFMA,
// swizzle key2(row)=((row>>1)^(row>>4))&3 on both stage-source and ds_read
// (r6: measured 0 conflicts), setprio, XCD swizzle, shuffle-free paired-silu
// epilogue (blk32-interleaved W1).
// Round 8: LDS cut to 2 buffers x 32 KiB = 64 KiB -> 2 blocks/CU (was 96 KiB
// -> 1 block/CU). Minimum-2-phase schedule: stage(t+1) -> compute(t) ->
// vmcnt(0)+barrier. Inter-block overlap (m114) hides the drain; all prior
// intra-block schedule tuning was null because 1 block/CU had no TLP.
// (r7 post-mortem: acc[4][4]x16 spilled to scratch -> 4.9GB fetch; reverted.)

typedef __bf16 bf16x8 __attribute__((ext_vector_type(8)));
typedef float f32x16 __attribute__((ext_vector_type(16)));

#define KD 1024
#define BUF_ELEMS 16384  // (256*32 A + 256*32 B) elems per buffer

__device__ __forceinline__ void gload_lds16(const void* g, void* lds_u) {
  __builtin_amdgcn_global_load_lds(
      (__attribute__((address_space(1))) void*)(uintptr_t)g,
      (__attribute__((address_space(3))) void*)(uint32_t)(uintptr_t)lds_u,
      16, 0, 0);
}

#define WAITB(N) do { \
  asm volatile("s_waitcnt vmcnt(" #N ")" ::: "memory"); \
  asm volatile("s_barrier" ::: "memory"); } while (0)

// ---------------- casts ----------------
__global__ void cast_f32_to_bf16_x8(const float* __restrict__ in,
                                    __bf16* __restrict__ out, int n8) {
  int i = blockIdx.x * blockDim.x + threadIdx.x;
  if (i >= n8) return;
  const float4* p = (const float4*)in;
  float4 v0 = p[2 * i];
  float4 v1 = p[2 * i + 1];
  bf16x8 o;
  o[0] = (__bf16)v0.x; o[1] = (__bf16)v0.y; o[2] = (__bf16)v0.z; o[3] = (__bf16)v0.w;
  o[4] = (__bf16)v1.x; o[5] = (__bf16)v1.y; o[6] = (__bf16)v1.z; o[7] = (__bf16)v1.w;
  ((bf16x8*)out)[i] = o;
}

// W1'' 32-row block interleave: out-row r, b=r>>5, t=r&31:
//   src row = (b&1)*1024 + (b>>1)*32 + t
// => n-frag pairs (j=0 x_val block, j=1 res block) cover the SAME G columns.
__global__ void cast_w1_blk32(const float* __restrict__ in,
                              __bf16* __restrict__ out) {
  int i = blockIdx.x * blockDim.x + threadIdx.x;  // 2048*128 threads
  int orow = i >> 7;
  int chunk = i & 127;
  int b = orow >> 5, t = orow & 31;
  int srow = (b & 1) * 1024 + (b >> 1) * 32 + t;
  const float4* p = (const float4*)(in + ((size_t)srow << 10) + (chunk << 3));
  float4 v0 = p[0], v1 = p[1];
  bf16x8 o;
  o[0] = (__bf16)v0.x; o[1] = (__bf16)v0.y; o[2] = (__bf16)v0.z; o[3] = (__bf16)v0.w;
  o[4] = (__bf16)v1.x; o[5] = (__bf16)v1.y; o[6] = (__bf16)v1.z; o[7] = (__bf16)v1.w;
  *(bf16x8*)(out + ((size_t)orow << 10) + (chunk << 3)) = o;
}

// ---------------- GEMM core ----------------
// Stage one 256x32 K-tile of A and B into buffer BUF. 4 gloads per wave.
template <int BUF>
__device__ __forceinline__ void stage_tile(const __bf16*& pa, const __bf16*& pb,
                                           __bf16* smw) {
  __bf16* d = smw + BUF * BUF_ELEMS;
  gload_lds16(pa, d);
  gload_lds16(pa + 128 * KD, d + 4096);
  gload_lds16(pb, d + 8192);
  gload_lds16(pb + 128 * KD, d + 12288);
  pa += 32;
  pb += 32;
}

// 32x32x16 MFMA. Per K-tile-32: 2 k-slices; 8 A + 4 B b128 reads; 16 MFMA.
// Chunk swizzle: phys = logical ^ key2(row); per frag parity the chunk offset
// alternates between o0 and o1 = o0^16 (key2 flips by 2 when frag idx is odd).
template <int BUF>
__device__ __forceinline__ void compute_tile(const __bf16* sm,
                                             int aRow, int bRow,
                                             int o0, int o1,
                                             f32x16 (&acc)[4][2]) {
  const __bf16* base = sm + BUF * BUF_ELEMS;
  bf16x8 a0[4], a1[4], b0[2], b1[2];
  // j even: ks0 -> o0, ks1 -> o1 ; j odd: swapped
  b0[0] = *(const bf16x8*)(base + bRow + o0);
  b1[0] = *(const bf16x8*)(base + bRow + o1);
  b0[1] = *(const bf16x8*)(base + bRow + 1024 + o1);
  b1[1] = *(const bf16x8*)(base + bRow + 1024 + o0);
#pragma unroll
  for (int i = 0; i < 4; ++i) {
    const int e0 = (i & 1) ? o1 : o0;
    const int e1 = (i & 1) ? o0 : o1;
    a0[i] = *(const bf16x8*)(base + aRow + i * 1024 + e0);
    a1[i] = *(const bf16x8*)(base + aRow + i * 1024 + e1);
  }
  __builtin_amdgcn_s_setprio(1);
#pragma unroll
  for (int i = 0; i < 4; ++i)
#pragma unroll
    for (int j = 0; j < 2; ++j)
      acc[i][j] = __builtin_amdgcn_mfma_f32_32x32x16_bf16(a0[i], b0[j], acc[i][j], 0, 0, 0);
#pragma unroll
  for (int i = 0; i < 4; ++i)
#pragma unroll
    for (int j = 0; j < 2; ++j)
      acc[i][j] = __builtin_amdgcn_mfma_f32_32x32x16_bf16(a1[i], b1[j], acc[i][j], 0, 0, 0);
  __builtin_amdgcn_s_setprio(0);
}

// Fills acc for the 256x256 tile at (m0, n0). A:[M][1024], B:[Nrows][1024].
__device__ __forceinline__ void gemm_core(const __bf16* __restrict__ A,
                                          const __bf16* __restrict__ B,
                                          __bf16* sm, long m0, long n0,
                                          f32x16 (&acc)[4][2]) {
  const int t = threadIdx.x;
  const int w = t >> 6;
  const int lane = t & 63;
  const int c31 = lane & 31;
  const int hi = lane >> 5;
  const int wr = w >> 2;  // 0..1 (M)
  const int wc = w & 3;   // 0..3 (N)

  // staging source: lane l covers LDS row w*16+(l>>2), phys slot l&3, which
  // must hold logical chunk (l&3) ^ key2(row); key2 = ((l>>3)&3) ^ (w&3).
  const int l = lane;
  const int stg_row = w * 16 + (l >> 2);
  const int stg_col = ((l & 3) ^ ((l >> 3) & 3) ^ (w & 3)) << 3;
  const __bf16* pa = A + (m0 + stg_row) * KD + stg_col;
  const __bf16* pb = B + (n0 + stg_row) * KD + stg_col;
  __bf16* smw = sm + w * 512;  // wave-uniform LDS base (1024B per wave-instr)

  // fragment read offsets. key_base = ((c31>>1)&3) ^ ((c31>>4)&1); frag idx
  // parity flips key by 2 (row bit 5 via r>>4). o1 = o0 ^ 16 elems.
  const int key_base = ((c31 >> 1) & 3) ^ ((c31 >> 4) & 1);
  const int o0 = (hi ^ key_base) << 3;
  const int o1 = o0 ^ 16;
  const int aRow = (wr * 128 + c31) * 32;          // + i*1024
  const int bRow = 8192 + (wc * 64 + c31) * 32;    // + j*1024

#pragma unroll
  for (int i = 0; i < 4; ++i)
#pragma unroll
    for (int j = 0; j < 2; ++j)
      acc[i][j] = (f32x16){0.f, 0.f, 0.f, 0.f, 0.f, 0.f, 0.f, 0.f,
                           0.f, 0.f, 0.f, 0.f, 0.f, 0.f, 0.f, 0.f};

  // prologue: stage tile 0 into buf0
  stage_tile<0>(pa, pb, smw);

  // 32 K-tiles, 2-phase: {wait cur; stage next into other; compute cur}
  for (int it = 0; it < 15; ++it) {
    WAITB(0);
    stage_tile<1>(pa, pb, smw);
    compute_tile<0>(sm, aRow, bRow, o0, o1, acc);
    WAITB(0);
    stage_tile<0>(pa, pb, smw);
    compute_tile<1>(sm, aRow, bRow, o0, o1, acc);
  }
  WAITB(0);
  stage_tile<1>(pa, pb, smw);
  compute_tile<0>(sm, aRow, bRow, o0, o1, acc);
  WAITB(0);
  compute_tile<1>(sm, aRow, bRow, o0, o1, acc);
}

// ---------------- GEMM1: Y = X @ W1''^T, paired-silu epilogue -> G bf16 -----
__global__ __launch_bounds__(512, 4)
void gemm1_silu(const __bf16* __restrict__ X, const __bf16* __restrict__ W1i,
                const float* __restrict__ in_b, __bf16* __restrict__ G) {
  __shared__ __bf16 sm[2 * BUF_ELEMS];  // 64 KiB -> 2 blocks/CU
  // XCD-aware bijective swizzle: nwg = 128*8 = 1024, divisible by 8
  const int bid = blockIdx.x;
  const int swz = (bid & 7) * 128 + (bid >> 3);
  const long m0 = (long)(swz >> 3) * 256;
  const long n0 = (long)(swz & 7) * 256;

  f32x16 acc[4][2];
  gemm_core(X, W1i, sm, m0, n0, acc);

  const int lane = threadIdx.x & 63;
  const int w = threadIdx.x >> 6;
  const int wr = w >> 2, wc = w & 3;
  const int c31 = lane & 31;
  const int hi = lane >> 5;

  // G column for this wave's frag pair: even block j=0 (x_val), odd j=1 (res)
  const int gc = ((int)n0 >> 1) + wc * 32 + c31;
  const float bx = in_b[gc];
  const float br = in_b[1024 + gc];

#pragma unroll
  for (int i = 0; i < 4; ++i)
#pragma unroll
    for (int reg = 0; reg < 16; ++reg) {
      const int row = wr * 128 + i * 32 + (reg & 3) + 8 * (reg >> 2) + 4 * hi;
      float xv = acc[i][0][reg] + bx;
      float rs = acc[i][1][reg] + br;
      float e1 = __expf(-xv);
      float e2 = __expf(-rs);
      float g = xv * rs * __builtin_amdgcn_rcpf((1.0f + e1) * (1.0f + e2));
      G[(m0 + row) * 1024 + gc] = (__bf16)g;
    }
}

// ---------------- GEMM2: OUT = G @ W2^T + out_b (fp32) ----------------
__global__ __launch_bounds__(512, 4)
void gemm2_bias(const __bf16* __restrict__ G, const __bf16* __restrict__ W2,
                const float* __restrict__ out_b, float* __restrict__ OUT) {
  __shared__ __bf16 sm[2 * BUF_ELEMS];
  // nwg = 128*4 = 512, divisible by 8
  const int bid = blockIdx.x;
  const int swz = (bid & 7) * 64 + (bid >> 3);
  const long m0 = (long)(swz >> 2) * 256;
  const long n0 = (long)(swz & 3) * 256;

  f32x16 acc[4][2];
  gemm_core(G, W2, sm, m0, n0, acc);

  const int lane = threadIdx.x & 63;
  const int w = threadIdx.x >> 6;
  const int wr = w >> 2, wc = w & 3;
  const int c31 = lane & 31;
  const int hi = lane >> 5;

  float ob[2];
#pragma unroll
  for (int j = 0; j < 2; ++j)
    ob[j] = out_b[(int)n0 + wc * 64 + j * 32 + c31];
#pragma unroll
  for (int i = 0; i < 4; ++i)
#pragma unroll
    for (int j = 0; j < 2; ++j)
#pragma unroll
      for (int reg = 0; reg < 16; ++reg) {
        const int row = wr * 128 + i * 32 + (reg & 3) + 8 * (reg >> 2) + 4 * hi;
        const int col = (int)n0 + wc * 64 + j * 32 + c31;
        OUT[(m0 + row) * 1024 + col] = acc[i][j][reg] + ob[j];
      }
}

extern "C" void kernel_launch(void* const* d_in, const int* in_sizes, int n_in,
                              void* d_out, int out_size, void* d_ws, size_t ws_size,
                              hipStream_t stream) {
  const float* x = (const float*)d_in[0];
  const float* in_w = (const float*)d_in[1];
  const float* in_b = (const float*)d_in[2];
  const float* out_w = (const float*)d_in[3];
  const float* out_b = (const float*)d_in[4];
  // d_in[5..8] (dt_w, dt_b, A, Dp) are dead in the reference.

  char* ws = (char*)d_ws;
  __bf16* xb = (__bf16*)(ws);                       // 67108864 B
  __bf16* w1b = (__bf16*)(ws + (size_t)67108864);   //  4194304 B (blk32 interleaved)
  __bf16* w2b = (__bf16*)(ws + (size_t)71303168);   //  2097152 B
  __bf16* gb = (__bf16*)(ws + (size_t)73400320);    // 67108864 B

  cast_f32_to_bf16_x8<<<dim3(16384), 256, 0, stream>>>(x, xb, 33554432 / 8);
  cast_w1_blk32<<<dim3(1024), 256, 0, stream>>>(in_w, w1b);
  cast_f32_to_bf16_x8<<<dim3(512), 256, 0, stream>>>(out_w, w2b, 1048576 / 8);

  gemm1_silu<<<dim3(1024), 512, 0, stream>>>(xb, w1b, in_b, gb);
  gemm2_bias<<<dim3(512), 512, 0, stream>>>(gb, w2b, out_b, (float*)d_out);
}

// Round 9
// 261.011 us; speedup vs baseline: 19.6528x; 14.5069x over previous
//
#include <hip/hip_runtime.h>
#include <cstdint>

// MambaBlock: out = (silu(x@in_w[:1024]^T+b0) * silu(x@in_w[1024:]^T+b1)) @ out_w^T + out_b
// M = 32768, K = 1024. dt_w/dt_b/A/Dp are dead inputs.
//
// Round 9 = round 6 verified core (266 us) + merged single-launch casts.
// Core: 256x256 tile, BK=32, 512 threads (8 waves, 2Mx4N), triple-buffered LDS
// (96 KiB, 1 block/CU), prefetch depth 2, counted vmcnt(4), 32x32x16 MFMA,
// swizzle key2(row)=((row>>1)^(row>>4))&3 on both stage-source and ds_read
// (measured 0 bank conflicts), setprio around MFMA cluster, bijective XCD
// swizzle, shuffle-free paired-silu epilogue (blk32-interleaved W1).
// r7 lesson: acc[4][4]x16 spills (VGPR>feasible) -> 25x slowdown.
// r8 lesson: launch_bounds(512,4) clamps VGPR to 64 -> spill; 2 blocks/CU is
// infeasible with a 128-float accumulator. 1 block/CU is the design point.

typedef __bf16 bf16x8 __attribute__((ext_vector_type(8)));
typedef float f32x16 __attribute__((ext_vector_type(16)));

#define KD 1024
#define BUF_ELEMS 16384  // (256*32 A + 256*32 B) elems per buffer

__device__ __forceinline__ void gload_lds16(const void* g, void* lds_u) {
  __builtin_amdgcn_global_load_lds(
      (__attribute__((address_space(1))) void*)(uintptr_t)g,
      (__attribute__((address_space(3))) void*)(uint32_t)(uintptr_t)lds_u,
      16, 0, 0);
}

#define WAITB(N) do { \
  asm volatile("s_waitcnt vmcnt(" #N ")" ::: "memory"); \
  asm volatile("s_barrier" ::: "memory"); } while (0)

// ---------------- merged cast kernel (single launch) ----------------
// blocks [0, 16384): x -> xb (f32->bf16, 8 elems/thread)
// blocks [16384, 17408): in_w -> w1b with 32-row block interleave
// blocks [17408, 17920): out_w -> w2b
__global__ void cast_all(const float* __restrict__ x, __bf16* __restrict__ xb,
                         const float* __restrict__ in_w, __bf16* __restrict__ w1b,
                         const float* __restrict__ out_w, __bf16* __restrict__ w2b) {
  const int b = blockIdx.x;
  if (b < 16384) {
    int i = b * 256 + threadIdx.x;  // < 4194304 = 33554432/8
    const float4* p = (const float4*)x;
    float4 v0 = p[2 * i];
    float4 v1 = p[2 * i + 1];
    bf16x8 o;
    o[0] = (__bf16)v0.x; o[1] = (__bf16)v0.y; o[2] = (__bf16)v0.z; o[3] = (__bf16)v0.w;
    o[4] = (__bf16)v1.x; o[5] = (__bf16)v1.y; o[6] = (__bf16)v1.z; o[7] = (__bf16)v1.w;
    ((bf16x8*)xb)[i] = o;
  } else if (b < 17408) {
    // W1'' 32-row block interleave: out-row r, blk=r>>5, t=r&31:
    //   src row = (blk&1)*1024 + (blk>>1)*32 + t
    int i = (b - 16384) * 256 + threadIdx.x;  // 2048*128 threads
    int orow = i >> 7;
    int chunk = i & 127;
    int bb = orow >> 5, t = orow & 31;
    int srow = (bb & 1) * 1024 + (bb >> 1) * 32 + t;
    const float4* p = (const float4*)(in_w + ((size_t)srow << 10) + (chunk << 3));
    float4 v0 = p[0], v1 = p[1];
    bf16x8 o;
    o[0] = (__bf16)v0.x; o[1] = (__bf16)v0.y; o[2] = (__bf16)v0.z; o[3] = (__bf16)v0.w;
    o[4] = (__bf16)v1.x; o[5] = (__bf16)v1.y; o[6] = (__bf16)v1.z; o[7] = (__bf16)v1.w;
    *(bf16x8*)(w1b + ((size_t)orow << 10) + (chunk << 3)) = o;
  } else {
    int i = (b - 17408) * 256 + threadIdx.x;  // < 131072 = 1048576/8
    const float4* p = (const float4*)out_w;
    float4 v0 = p[2 * i];
    float4 v1 = p[2 * i + 1];
    bf16x8 o;
    o[0] = (__bf16)v0.x; o[1] = (__bf16)v0.y; o[2] = (__bf16)v0.z; o[3] = (__bf16)v0.w;
    o[4] = (__bf16)v1.x; o[5] = (__bf16)v1.y; o[6] = (__bf16)v1.z; o[7] = (__bf16)v1.w;
    ((bf16x8*)w2b)[i] = o;
  }
}

// ---------------- GEMM core ----------------
// Stage one 256x32 K-tile of A and B into buffer BUF. 4 gloads per wave.
template <int BUF>
__device__ __forceinline__ void stage_tile(const __bf16*& pa, const __bf16*& pb,
                                           __bf16* smw) {
  __bf16* d = smw + BUF * BUF_ELEMS;
  gload_lds16(pa, d);
  gload_lds16(pa + 128 * KD, d + 4096);
  gload_lds16(pb, d + 8192);
  gload_lds16(pb + 128 * KD, d + 12288);
  pa += 32;
  pb += 32;
}

// 32x32x16 MFMA. Per K-tile-32: 2 k-slices; 8 A + 4 B b128 reads; 16 MFMA.
// Chunk swizzle: phys = logical ^ key2(row); per frag parity the chunk offset
// alternates between o0 and o1 = o0^16 (key2 flips by 2 when frag idx is odd).
template <int BUF>
__device__ __forceinline__ void compute_tile(const __bf16* sm,
                                             int aRow, int bRow,
                                             int o0, int o1,
                                             f32x16 (&acc)[4][2]) {
  const __bf16* base = sm + BUF * BUF_ELEMS;
  bf16x8 a0[4], a1[4], b0[2], b1[2];
  // j even: ks0 -> o0, ks1 -> o1 ; j odd: swapped
  b0[0] = *(const bf16x8*)(base + bRow + o0);
  b1[0] = *(const bf16x8*)(base + bRow + o1);
  b0[1] = *(const bf16x8*)(base + bRow + 1024 + o1);
  b1[1] = *(const bf16x8*)(base + bRow + 1024 + o0);
#pragma unroll
  for (int i = 0; i < 4; ++i) {
    const int e0 = (i & 1) ? o1 : o0;
    const int e1 = (i & 1) ? o0 : o1;
    a0[i] = *(const bf16x8*)(base + aRow + i * 1024 + e0);
    a1[i] = *(const bf16x8*)(base + aRow + i * 1024 + e1);
  }
  __builtin_amdgcn_s_setprio(1);
#pragma unroll
  for (int i = 0; i < 4; ++i)
#pragma unroll
    for (int j = 0; j < 2; ++j)
      acc[i][j] = __builtin_amdgcn_mfma_f32_32x32x16_bf16(a0[i], b0[j], acc[i][j], 0, 0, 0);
#pragma unroll
  for (int i = 0; i < 4; ++i)
#pragma unroll
    for (int j = 0; j < 2; ++j)
      acc[i][j] = __builtin_amdgcn_mfma_f32_32x32x16_bf16(a1[i], b1[j], acc[i][j], 0, 0, 0);
  __builtin_amdgcn_s_setprio(0);
}

// Fills acc for the 256x256 tile at (m0, n0). A:[M][1024], B:[Nrows][1024].
__device__ __forceinline__ void gemm_core(const __bf16* __restrict__ A,
                                          const __bf16* __restrict__ B,
                                          __bf16* sm, long m0, long n0,
                                          f32x16 (&acc)[4][2]) {
  const int t = threadIdx.x;
  const int w = t >> 6;
  const int lane = t & 63;
  const int c31 = lane & 31;
  const int hi = lane >> 5;
  const int wr = w >> 2;  // 0..1 (M)
  const int wc = w & 3;   // 0..3 (N)

  // staging source: lane l covers LDS row w*16+(l>>2), phys slot l&3, which
  // must hold logical chunk (l&3) ^ key2(row); key2 = ((l>>3)&3) ^ (w&3).
  const int l = lane;
  const int stg_row = w * 16 + (l >> 2);
  const int stg_col = ((l & 3) ^ ((l >> 3) & 3) ^ (w & 3)) << 3;
  const __bf16* pa = A + (m0 + stg_row) * KD + stg_col;
  const __bf16* pb = B + (n0 + stg_row) * KD + stg_col;
  __bf16* smw = sm + w * 512;  // wave-uniform LDS base (1024B per wave-instr)

  // fragment read offsets. key_base = ((c31>>1)&3) ^ ((c31>>4)&1); frag idx
  // parity flips key by 2 (row bit 5 via r>>4). o1 = o0 ^ 16 elems.
  const int key_base = ((c31 >> 1) & 3) ^ ((c31 >> 4) & 1);
  const int o0 = (hi ^ key_base) << 3;
  const int o1 = o0 ^ 16;
  const int aRow = (wr * 128 + c31) * 32;          // + i*1024
  const int bRow = 8192 + (wc * 64 + c31) * 32;    // + j*1024

#pragma unroll
  for (int i = 0; i < 4; ++i)
#pragma unroll
    for (int j = 0; j < 2; ++j)
      acc[i][j] = (f32x16){0.f, 0.f, 0.f, 0.f, 0.f, 0.f, 0.f, 0.f,
                           0.f, 0.f, 0.f, 0.f, 0.f, 0.f, 0.f, 0.f};

  // prologue: stage tiles 0,1
  stage_tile<0>(pa, pb, smw);
  stage_tile<1>(pa, pb, smw);

  // tiles 0..29: compute buf t%3, stage tile t+2 into buf (t+2)%3
  for (int it = 0; it < 10; ++it) {
    WAITB(4); stage_tile<2>(pa, pb, smw);
    compute_tile<0>(sm, aRow, bRow, o0, o1, acc);
    WAITB(4); stage_tile<0>(pa, pb, smw);
    compute_tile<1>(sm, aRow, bRow, o0, o1, acc);
    WAITB(4); stage_tile<1>(pa, pb, smw);
    compute_tile<2>(sm, aRow, bRow, o0, o1, acc);
  }
  // tail: tiles 30 (buf0), 31 (buf1)
  WAITB(4); compute_tile<0>(sm, aRow, bRow, o0, o1, acc);
  WAITB(0); compute_tile<1>(sm, aRow, bRow, o0, o1, acc);
}

// ---------------- GEMM1: Y = X @ W1''^T, paired-silu epilogue -> G bf16 -----
__global__ __launch_bounds__(512, 2)
void gemm1_silu(const __bf16* __restrict__ X, const __bf16* __restrict__ W1i,
                const float* __restrict__ in_b, __bf16* __restrict__ G) {
  __shared__ __bf16 sm[3 * BUF_ELEMS];
  // XCD-aware bijective swizzle: nwg = 128*8 = 1024, divisible by 8
  const int bid = blockIdx.x;
  const int swz = (bid & 7) * 128 + (bid >> 3);
  const long m0 = (long)(swz >> 3) * 256;
  const long n0 = (long)(swz & 7) * 256;

  f32x16 acc[4][2];
  gemm_core(X, W1i, sm, m0, n0, acc);

  const int lane = threadIdx.x & 63;
  const int w = threadIdx.x >> 6;
  const int wr = w >> 2, wc = w & 3;
  const int c31 = lane & 31;
  const int hi = lane >> 5;

  // G column for this wave's frag pair: even block j=0 (x_val), odd j=1 (res)
  const int gc = ((int)n0 >> 1) + wc * 32 + c31;
  const float bx = in_b[gc];
  const float br = in_b[1024 + gc];

#pragma unroll
  for (int i = 0; i < 4; ++i)
#pragma unroll
    for (int reg = 0; reg < 16; ++reg) {
      const int row = wr * 128 + i * 32 + (reg & 3) + 8 * (reg >> 2) + 4 * hi;
      float xv = acc[i][0][reg] + bx;
      float rs = acc[i][1][reg] + br;
      float e1 = __expf(-xv);
      float e2 = __expf(-rs);
      float g = xv * rs * __builtin_amdgcn_rcpf((1.0f + e1) * (1.0f + e2));
      G[(m0 + row) * 1024 + gc] = (__bf16)g;
    }
}

// ---------------- GEMM2: OUT = G @ W2^T + out_b (fp32) ----------------
__global__ __launch_bounds__(512, 2)
void gemm2_bias(const __bf16* __restrict__ G, const __bf16* __restrict__ W2,
                const float* __restrict__ out_b, float* __restrict__ OUT) {
  __shared__ __bf16 sm[3 * BUF_ELEMS];
  // nwg = 128*4 = 512, divisible by 8
  const int bid = blockIdx.x;
  const int swz = (bid & 7) * 64 + (bid >> 3);
  const long m0 = (long)(swz >> 2) * 256;
  const long n0 = (long)(swz & 3) * 256;

  f32x16 acc[4][2];
  gemm_core(G, W2, sm, m0, n0, acc);

  const int lane = threadIdx.x & 63;
  const int w = threadIdx.x >> 6;
  const int wr = w >> 2, wc = w & 3;
  const int c31 = lane & 31;
  const int hi = lane >> 5;

  float ob[2];
#pragma unroll
  for (int j = 0; j < 2; ++j)
    ob[j] = out_b[(int)n0 + wc * 64 + j * 32 + c31];
#pragma unroll
  for (int i = 0; i < 4; ++i)
#pragma unroll
    for (int j = 0; j < 2; ++j)
#pragma unroll
      for (int reg = 0; reg < 16; ++reg) {
        const int row = wr * 128 + i * 32 + (reg & 3) + 8 * (reg >> 2) + 4 * hi;
        const int col = (int)n0 + wc * 64 + j * 32 + c31;
        OUT[(m0 + row) * 1024 + col] = acc[i][j][reg] + ob[j];
      }
}

extern "C" void kernel_launch(void* const* d_in, const int* in_sizes, int n_in,
                              void* d_out, int out_size, void* d_ws, size_t ws_size,
                              hipStream_t stream) {
  const float* x = (const float*)d_in[0];
  const float* in_w = (const float*)d_in[1];
  const float* in_b = (const float*)d_in[2];
  const float* out_w = (const float*)d_in[3];
  const float* out_b = (const float*)d_in[4];
  // d_in[5..8] (dt_w, dt_b, A, Dp) are dead in the reference.

  char* ws = (char*)d_ws;
  __bf16* xb = (__bf16*)(ws);                       // 67108864 B
  __bf16* w1b = (__bf16*)(ws + (size_t)67108864);   //  4194304 B (blk32 interleaved)
  __bf16* w2b = (__bf16*)(ws + (size_t)71303168);   //  2097152 B
  __bf16* gb = (__bf16*)(ws + (size_t)73400320);    // 67108864 B

  cast_all<<<dim3(17920), 256, 0, stream>>>(x, xb, in_w, w1b, out_w, w2b);
  gemm1_silu<<<dim3(1024), 512, 0, stream>>>(xb, w1b, in_b, gb);
  gemm2_bias<<<dim3(512), 512, 0, stream>>>(gb, w2b, out_b, (float*)d_out);
}